// Round 9
// baseline (85.838 us; speedup 1.0000x reference)
//
#include <hip/hip_runtime.h>
#include <hip/hip_fp16.h>
#include <math.h>

// B=8, C=64, H=W=64, O=128, K=3, N=9, stride=1, pad=1
// ws layout (8.61 MB):
//   xTh  @ 0        : fp16 hi(x) [8][4096 pix][64 c] = 4,194,304 B
//   xTl  @ 4194304  : fp16 lo(x) [8][4096 pix][64 c] = 4,194,304 B
//   WtH  @ 8388608  : fp16 [9][128 o][64 c]          =   147,456 B
//   WtSh @ 8536064  : fp16 [9][32 ch][64 c]          =    36,864 B
//   WtSl @ 8572928  : fp16 [9][32 ch][64 c]          =    36,864 B

typedef _Float16 half8_t __attribute__((ext_vector_type(8)));
typedef float f32x4 __attribute__((ext_vector_type(4)));

// ---------------------------------------------------------------------------
// k_pre: blocks 0..511  : x (B,C,H,W) f32 -> xTh/xTl (B,HW,C) split fp16
//        blocks 512..871: conv_w -> WtH ; shift/mod weights -> WtSh/WtSl
// ---------------------------------------------------------------------------
__global__ __launch_bounds__(256) void k_pre(const float* __restrict__ x,
                                             const float* __restrict__ cw,
                                             const float* __restrict__ shift_w,
                                             const float* __restrict__ mod_w,
                                             __half* __restrict__ xTh,
                                             __half* __restrict__ xTl,
                                             __half* __restrict__ WtH,
                                             __half* __restrict__ WtSh,
                                             __half* __restrict__ WtSl) {
    __shared__ float tile[64][65];
    int bid = blockIdx.x;
    int t = threadIdx.x;
    if (bid < 512) {
        int b = bid >> 6, pt = bid & 63;
        int lane = t & 63, cq = t >> 6;
        const float* xb = x + ((size_t)b << 18);
#pragma unroll
        for (int r = 0; r < 16; ++r) {
            int c = cq * 16 + r;
            tile[c][lane] = xb[((size_t)c << 12) + pt * 64 + lane];
        }
        __syncthreads();
        int p = t >> 2, qc = t & 3;
        __align__(16) _Float16 hh[16];
        __align__(16) _Float16 ll[16];
#pragma unroll
        for (int k = 0; k < 16; ++k) {
            float v = tile[qc * 16 + k][p];
            _Float16 h = (_Float16)v;
            hh[k] = h;
            ll[k] = (_Float16)(v - (float)h);
        }
        size_t off = ((size_t)b << 18) + (size_t)(pt * 64 + p) * 64 + qc * 16;
        ((uint4*)(xTh + off))[0] = ((uint4*)hh)[0];
        ((uint4*)(xTh + off))[1] = ((uint4*)hh)[1];
        ((uint4*)(xTl + off))[0] = ((uint4*)ll)[0];
        ((uint4*)(xTl + off))[1] = ((uint4*)ll)[1];
    } else {
        int u = (bid - 512) * 256 + t;
        if (u < 73728) {
            int c = u & 63;
            int o = (u >> 6) & 127;
            int n = u >> 13;
            WtH[u] = __float2half_rn(cw[(o * 64 + c) * 9 + n]);
        } else {
            int v = u - 73728;
            if (v < 18432) {
                int c = v & 63;
                int ch = (v >> 6) & 31;
                int tap = v >> 11;
                float w = 0.f;
                if (ch < 18) w = shift_w[(ch * 64 + c) * 9 + tap];
                else if (ch < 27) w = mod_w[((ch - 18) * 64 + c) * 9 + tap];
                _Float16 h = (_Float16)w;
                _Float16 lo = (_Float16)(w - (float)h);
                WtSh[v] = *(__half*)&h;
                WtSl[v] = *(__half*)&lo;
            }
        }
    }
}

// ---------------------------------------------------------------------------
// k_wave: ONE WAVE per block; wave owns 16 pixels x all 128 outputs.
//   grid 2048 x 64 thr, __launch_bounds__(64,4) -> 16 blocks/CU, VGPR<=128.
//   Waves fully independent: barriers only at the 2 record handoffs (LDS).
//   Phase A: stage1 conv, 108 split-fp16 MFMA, K looped in-wave (no reduce).
//   Phase B: 9 taps, A-fragment built IN REGISTERS from 8 reg-gathers
//            (lane l = pixel l15, c-chunk lhi — exactly the MFMA A layout);
//            no ds_write/read, no barriers; next-tap gathers prefetched.
//   Epilogue: acc rows = pixels lhi*4+v4 -> direct float4 global stores.
// ---------------------------------------------------------------------------
__global__ __launch_bounds__(64, 4) void k_wave(
    const __half* __restrict__ xTh, const __half* __restrict__ xTl,
    const __half* __restrict__ WtH, const __half* __restrict__ WtSh,
    const __half* __restrict__ WtSl, const float* __restrict__ shift_b,
    const float* __restrict__ mod_b, float* __restrict__ out) {
    __shared__ float Cw[16][36];     // stage1 C transpose (2-way conflicts = free)
    __shared__ uint4 recA[9][16];    // per-pixel records: w0,w1,mod,pad

    int l = threadIdx.x;
    int l15 = l & 15, lhi = l >> 4;

    // XCD swizzle: 2048 = 8 XCD * 256; each XCD owns one batch image.
    int bid = blockIdx.x;
    int bk = (bid & 7) * 256 + (bid >> 3);
    int b = bk >> 8;
    int u = bk & 255;
    int row = u >> 2;
    int col0 = (u & 3) << 4;

    const __half* xbh = xTh + ((size_t)b << 18);
    const __half* xbl = xTl + ((size_t)b << 18);

    // ---------------- Phase A: stage1 conv (split-fp16 MFMA) ----------------
    {
        f32x4 accA0 = {0.f, 0.f, 0.f, 0.f};
        f32x4 accA1 = {0.f, 0.f, 0.f, 0.f};
        int colp = col0 + l15;
        half8_t Z;
#pragma unroll
        for (int e = 0; e < 8; ++e) Z[e] = (_Float16)0.f;

#pragma unroll
        for (int tr = 0; tr < 3; ++tr) {
            int rsh = row + tr - 1;
            if ((unsigned)rsh >= 64u) continue;      // wave-uniform border skip
#pragma unroll
            for (int tc = 0; tc < 3; ++tc) {
                int tap = tr * 3 + tc;
                int cs = colp + tc - 1;
                bool vcol = (unsigned)cs < 64u;
                size_t poff = (size_t)((rsh << 6) + (vcol ? cs : 0)) * 64 + (lhi << 3);
                const __half* wsh = WtSh + tap * 2048 + l15 * 64 + (lhi << 3);
                const __half* wsl = WtSl + tap * 2048 + l15 * 64 + (lhi << 3);
#pragma unroll
                for (int chf = 0; chf < 2; ++chf) {
                    half8_t Ah = *(const half8_t*)(xbh + poff + chf * 32);
                    half8_t Al = *(const half8_t*)(xbl + poff + chf * 32);
                    if (!vcol) { Ah = Z; Al = Z; }
#pragma unroll
                    for (int nf = 0; nf < 2; ++nf) {
                        half8_t Bh = *(const half8_t*)(wsh + chf * 32 + nf * 1024);
                        half8_t Bl = *(const half8_t*)(wsl + chf * 32 + nf * 1024);
                        if (nf == 0) {
                            accA0 = __builtin_amdgcn_mfma_f32_16x16x32_f16(Ah, Bh, accA0, 0, 0, 0);
                            accA0 = __builtin_amdgcn_mfma_f32_16x16x32_f16(Ah, Bl, accA0, 0, 0, 0);
                            accA0 = __builtin_amdgcn_mfma_f32_16x16x32_f16(Al, Bh, accA0, 0, 0, 0);
                        } else {
                            accA1 = __builtin_amdgcn_mfma_f32_16x16x32_f16(Ah, Bh, accA1, 0, 0, 0);
                            accA1 = __builtin_amdgcn_mfma_f32_16x16x32_f16(Ah, Bl, accA1, 0, 0, 0);
                            accA1 = __builtin_amdgcn_mfma_f32_16x16x32_f16(Al, Bh, accA1, 0, 0, 0);
                        }
                    }
                }
            }
        }
        // C transpose to LDS: lane holds ch=l15(+16) for pixels lhi*4+v4
#pragma unroll
        for (int v4 = 0; v4 < 4; ++v4) {
            Cw[(lhi << 2) + v4][l15] = accA0[v4];
            Cw[(lhi << 2) + v4][16 + l15] = accA1[v4];
        }
    }
    __syncthreads();

    // ---------------- records: 16 pix x 9 n (144 tasks / 64 lanes) ----------------
#pragma unroll
    for (int j = 0; j < 3; ++j) {
        int rid = j * 64 + l;
        if (rid < 144) {
            int n = rid >> 4;
            int p = rid & 15;
            float sx = Cw[p][n];
            float sy = Cw[p][9 + n];
            float sm = Cw[p][18 + n];
            int jj = col0 + p;

            float px = ((sx + shift_b[n]) + (float)(n / 3 - 1)) + (float)(row + 1);
            float py = ((sy + shift_b[9 + n]) + (float)(n % 3 - 1)) + (float)(jj + 1);
            float mod = 1.f / (1.f + expf(-(sm + mod_b[n])));

            float fx = floorf(px), fy = floorf(py);
            int ltx = (int)fminf(fmaxf(fx, 0.f), 63.f);
            int lty = (int)fminf(fmaxf(fy, 0.f), 63.f);
            int rbx = (int)fminf(fmaxf(fx + 1.f, 0.f), 63.f);
            int rby = (int)fminf(fmaxf(fy + 1.f, 0.f), 63.f);
            int pxi = (int)fminf(fmaxf(px, 0.f), 63.f);
            int pyi = (int)fminf(fmaxf(py, 0.f), 63.f);

            int g_lt = (1 + ltx - pxi) * (1 + lty - pyi);
            int g_rb = (1 - rbx + pxi) * (1 - rby + pyi);
            int g_lb = (1 + ltx - pxi) * (1 + rby - pyi);
            int g_rt = (1 - rbx + pxi) * (1 - lty + pyi);

            int qxa[4] = {ltx, rbx, ltx, rbx};
            int qya[4] = {lty, rby, rby, lty};
            int gga[4] = {g_lt, g_rb, g_lb, g_rt};
            unsigned w0 = 0, w1 = 0;
#pragma unroll
            for (int jq = 0; jq < 4; ++jq) {
                bool valid = (qxa[jq] >= 1) && (qya[jq] >= 1);
                unsigned idx = valid ? (unsigned)((qxa[jq] - 1) * 64 + (qya[jq] - 1)) : 0u;
                unsigned gc = valid ? (unsigned)gga[jq] : 0u;   // 0..2
                if (jq < 2) w0 |= idx << (12 * jq); else w1 |= idx << (12 * (jq - 2));
                w0 |= gc << (24 + 2 * jq);
            }
            recA[n][p] = make_uint4(w0, w1, __float_as_uint(mod), 0u);
        }
    }
    __syncthreads();

    // ---------------- Phase B: 9 taps, barrier-free, reg-resident A ----------------
    f32x4 acc[8];
#pragma unroll
    for (int g = 0; g < 8; ++g) acc[g] = (f32x4){0.f, 0.f, 0.f, 0.f};

#define LOADG(Gd, rcv)                                                        \
    {                                                                         \
        int id0 = (int)((rcv).x & 0xFFF);                                     \
        int id1 = (int)(((rcv).x >> 12) & 0xFFF);                             \
        int id2 = (int)((rcv).y & 0xFFF);                                     \
        int id3 = (int)(((rcv).y >> 12) & 0xFFF);                             \
        const __half* p0 = xbh + (id0 << 6) + (lhi << 3);                     \
        const __half* p1 = xbh + (id1 << 6) + (lhi << 3);                     \
        const __half* p2 = xbh + (id2 << 6) + (lhi << 3);                     \
        const __half* p3 = xbh + (id3 << 6) + (lhi << 3);                     \
        Gd[0] = *(const uint4*)(p0); Gd[1] = *(const uint4*)(p0 + 32);        \
        Gd[2] = *(const uint4*)(p1); Gd[3] = *(const uint4*)(p1 + 32);        \
        Gd[4] = *(const uint4*)(p2); Gd[5] = *(const uint4*)(p2 + 32);        \
        Gd[6] = *(const uint4*)(p3); Gd[7] = *(const uint4*)(p3 + 32);        \
    }

    uint4 rc = recA[0][l15];
    uint4 G[8];
    LOADG(G, rc);

#pragma unroll
    for (int n = 0; n < 9; ++n) {
        // combine gathers -> A fragments (lane = pixel l15, k-chunk lhi)
        float mod = __uint_as_float(rc.z);
        half8_t Af[2];
#pragma unroll
        for (int ks = 0; ks < 2; ++ks) {
            __half2 a0(0, 0), a1(0, 0), a2(0, 0), a3(0, 0);
#pragma unroll
            for (int j = 0; j < 4; ++j) {
                float wf = (float)((rc.x >> (24 + 2 * j)) & 3) * mod;
                __half2 wh2 = __half2(__float2half_rn(wf), __float2half_rn(wf));
                const __half2* vv = (const __half2*)&G[j * 2 + ks];
                a0 = __hfma2(wh2, vv[0], a0);
                a1 = __hfma2(wh2, vv[1], a1);
                a2 = __hfma2(wh2, vv[2], a2);
                a3 = __hfma2(wh2, vv[3], a3);
            }
            __align__(16) __half2 tmp[4] = {a0, a1, a2, a3};
            Af[ks] = *(half8_t*)tmp;
        }

        // prefetch next tap (no barrier will drain these)
        uint4 rcn;
        uint4 Gn[8];
        if (n < 8) {
            rcn = recA[n + 1][l15];
            LOADG(Gn, rcn);
        }

        // 16 MFMA with B chunks of 4 (VGPR cap)
        const __half* Wn = WtH + n * 8192;
#pragma unroll
        for (int ks = 0; ks < 2; ++ks)
#pragma unroll
            for (int oc = 0; oc < 2; ++oc) {
                uint4 Bv[4];
#pragma unroll
                for (int g = 0; g < 4; ++g)
                    Bv[g] = *(const uint4*)(Wn + (((oc * 4 + g) * 16 + l15) << 6) +
                                            ks * 32 + (lhi << 3));
#pragma unroll
                for (int g = 0; g < 4; ++g) {
                    half8_t Bf = *(half8_t*)&Bv[g];
                    acc[oc * 4 + g] = __builtin_amdgcn_mfma_f32_16x16x32_f16(
                        Af[ks], Bf, acc[oc * 4 + g], 0, 0, 0);
                }
            }

        if (n < 8) {
            rc = rcn;
#pragma unroll
            for (int j = 0; j < 8; ++j) G[j] = Gn[j];
        }
    }
#undef LOADG

    // ---------------- Epilogue: direct float4 stores ----------------
    float* ob = out + ((size_t)b << 19);
    int prow = (row << 6) + col0 + (lhi << 2);
#pragma unroll
    for (int og = 0; og < 8; ++og) {
        float* dst = ob + (((size_t)(og * 16 + l15)) << 12) + prow;
        *(float4*)dst = *(float4*)&acc[og];
    }
}

// ---------------------------------------------------------------------------
extern "C" void kernel_launch(void* const* d_in, const int* in_sizes, int n_in,
                              void* d_out, int out_size, void* d_ws, size_t ws_size,
                              hipStream_t stream) {
    const float* x = (const float*)d_in[0];
    const float* shift_w = (const float*)d_in[1];
    const float* shift_b = (const float*)d_in[2];
    const float* mod_w = (const float*)d_in[3];
    const float* mod_b = (const float*)d_in[4];
    const float* conv_w = (const float*)d_in[5];
    float* out = (float*)d_out;

    char* ws = (char*)d_ws;
    __half* xTh = (__half*)ws;                       // 4 MB
    __half* xTl = (__half*)(ws + 4194304);           // 4 MB
    __half* WtH = (__half*)(ws + 8388608);           // 144 KB
    __half* WtSh = (__half*)(ws + 8536064);          // 36 KB
    __half* WtSl = (__half*)(ws + 8572928);          // 36 KB  (total 8.61 MB)

    k_pre<<<dim3(872), dim3(256), 0, stream>>>(x, conv_w, shift_w, mod_w,
                                               xTh, xTl, WtH, WtSh, WtSl);
    k_wave<<<dim3(2048), dim3(64), 0, stream>>>(xTh, xTl, WtH, WtSh, WtSl,
                                                shift_b, mod_b, out);
}